// Round 1
// baseline (137950.183 us; speedup 1.0000x reference)
//
#include <hip/hip_runtime.h>

#define T_LEN 131072
#define HDIM  100
#define START_T 0   // keep 0 this round: full-sequence correctness baseline

__device__ __forceinline__ float fast_rcp(float x) { return __builtin_amdgcn_rcpf(x); }

// sigmoid(u) = 1/(1+exp(-u)); tanh(z) = 2*sigmoid(2z)-1  (one exp + one rcp either way)

__global__ __launch_bounds__(448, 1)
void lstm_seq_kernel(const float* __restrict__ input_seq,
                     const float* __restrict__ W_ih,
                     const float* __restrict__ W_hh,
                     const float* __restrict__ b_ih,
                     const float* __restrict__ b_hh,
                     const float* __restrict__ W_lin,
                     const float* __restrict__ b_lin,
                     float* __restrict__ out)
{
    __shared__ __align__(16) float h_lds[104];   // h[100], float4-aligned
    __shared__ float g_lds[400];                 // gate values i|f|g|o

    const int tid = threadIdx.x;
    const bool rowAct = tid < 400;
    const int r = tid;
    const bool isg = (r >= 200) && (r < 300);    // tanh rows (g gate)

    // --- one-time: W_hh row + W_ih row + fused bias into registers ---
    float w[HDIM];
    float wi0 = 0.f, wi1 = 0.f, wi2 = 0.f, wi3 = 0.f, wi4 = 0.f;
    float bias = 0.f;
    if (rowAct) {
        #pragma unroll
        for (int j = 0; j < HDIM; ++j) w[j] = W_hh[r * HDIM + j];
        wi0 = W_ih[r * 5 + 0];
        wi1 = W_ih[r * 5 + 1];
        wi2 = W_ih[r * 5 + 2];
        wi3 = W_ih[r * 5 + 3];
        wi4 = W_ih[r * 5 + 4];
        bias = b_ih[r] + b_hh[r];
    }

    float c = 0.f;                               // cell state, thread j<100 owns c_j
    if (tid < 104) h_lds[tid] = 0.f;
    __syncthreads();

    // x_t pipeline: uniform loads -> SGPRs, 1-step lookahead
    float xc0 = input_seq[START_T * 5 + 0];
    float xc1 = input_seq[START_T * 5 + 1];
    float xc2 = input_seq[START_T * 5 + 2];
    float xc3 = input_seq[START_T * 5 + 3];
    float xc4 = input_seq[START_T * 5 + 4];

    const float4* __restrict__ h4 = (const float4*)h_lds;

    for (int t = START_T; t < T_LEN; ++t) {
        // prefetch next step's x (uniform -> scalar loads, hidden under matvec)
        const int tn = (t + 1 < T_LEN) ? (t + 1) : t;
        const float xn0 = input_seq[tn * 5 + 0];
        const float xn1 = input_seq[tn * 5 + 1];
        const float xn2 = input_seq[tn * 5 + 2];
        const float xn3 = input_seq[tn * 5 + 3];
        const float xn4 = input_seq[tn * 5 + 4];

        if (rowAct) {
            // z_r = bias + W_ih[r]*x_t + W_hh[r]*h   (4 independent FMA chains)
            float a0 = bias + wi0 * xc0 + wi1 * xc1 + wi2 * xc2 + wi3 * xc3 + wi4 * xc4;
            float a1 = 0.f, a2 = 0.f, a3 = 0.f;
            #pragma unroll
            for (int q = 0; q < 25; ++q) {
                const float4 hv = h4[q];          // LDS broadcast read (b128)
                a0 += w[4 * q + 0] * hv.x;
                a1 += w[4 * q + 1] * hv.y;
                a2 += w[4 * q + 2] * hv.z;
                a3 += w[4 * q + 3] * hv.w;
            }
            const float z = (a0 + a1) + (a2 + a3);

            // branchless gate nonlinearity: one exp + one rcp for all rows
            const float u  = isg ? 2.f * z : z;
            const float e  = __expf(-u);
            const float sg = fast_rcp(1.f + e);
            const float gv = isg ? (2.f * sg - 1.f) : sg;
            g_lds[r] = gv;
        }
        __syncthreads();                          // gates visible; old-h reads done

        if (tid < HDIM) {
            const float iv = g_lds[tid];
            const float fv = g_lds[100 + tid];
            const float gg = g_lds[200 + tid];
            const float ov = g_lds[300 + tid];
            c = fv * c + iv * gg;
            // tanh(c) = 2*sigmoid(2c)-1
            const float e2 = __expf(-2.f * c);
            const float th = 2.f * fast_rcp(1.f + e2) - 1.f;
            h_lds[tid] = ov * th;
        }
        __syncthreads();                          // new h visible for next step

        xc0 = xn0; xc1 = xn1; xc2 = xn2; xc3 = xn3; xc4 = xn4;
    }

    // epilogue: out = b_lin + W_lin . h_T   (O == 1, one-time cost)
    if (tid == 0) {
        float acc = b_lin[0];
        #pragma unroll
        for (int j = 0; j < HDIM; ++j) acc += W_lin[j] * h_lds[j];
        out[0] = acc;
    }
}

extern "C" void kernel_launch(void* const* d_in, const int* in_sizes, int n_in,
                              void* d_out, int out_size, void* d_ws, size_t ws_size,
                              hipStream_t stream) {
    const float* input_seq = (const float*)d_in[0];
    const float* W_ih      = (const float*)d_in[1];
    const float* W_hh      = (const float*)d_in[2];
    const float* b_ih      = (const float*)d_in[3];
    const float* b_hh      = (const float*)d_in[4];
    const float* W_lin     = (const float*)d_in[5];
    const float* b_lin     = (const float*)d_in[6];
    float* out = (float*)d_out;

    lstm_seq_kernel<<<1, 448, 0, stream>>>(input_seq, W_ih, W_hh, b_ih, b_hh,
                                           W_lin, b_lin, out);
}

// Round 2
// 116680.530 us; speedup vs baseline: 1.1823x; 1.1823x over previous
//
#include <hip/hip_runtime.h>

#define T_LEN 131072
#define HDIM  100

// thread layout: tid = 4*j + g   (j = hidden index 0..99, g = gate 0:i 1:f 2:g 3:o)
// row in W_hh/W_ih/b = 100*g + j
// Per step: matvec (weights in explicit-register float4s, h broadcast from LDS),
// gate nonlinearity, DPP quad_perm gate exchange (VALU, no LDS), replicated c
// update in all 4 lanes of the quad, g==0 lane writes h to the OTHER buffer,
// ONE barrier per step (double-buffered h makes this race-free).

__global__ __launch_bounds__(448, 1)
void lstm_seq_kernel(const float* __restrict__ input_seq,
                     const float* __restrict__ W_ih,
                     const float* __restrict__ W_hh,
                     const float* __restrict__ b_ih,
                     const float* __restrict__ b_hh,
                     const float* __restrict__ W_lin,
                     const float* __restrict__ b_lin,
                     float* __restrict__ out)
{
    __shared__ __align__(16) float hbuf[2][104];   // double-buffered h

    const int tid = threadIdx.x;
    const int j   = tid >> 2;          // 0..111
    const int g   = tid & 3;           // gate id
    const bool act = tid < 400;
    const int row = act ? (100 * g + j) : 0;
    const bool isg = (g == 2);         // tanh gate

    // ---- one-time: weight row into 25 explicitly-named float4 registers ----
    const float4* __restrict__ wp = (const float4*)(W_hh + row * HDIM);
#define WDECL(q) const float4 w##q = wp[q];
    WDECL(0)  WDECL(1)  WDECL(2)  WDECL(3)  WDECL(4)
    WDECL(5)  WDECL(6)  WDECL(7)  WDECL(8)  WDECL(9)
    WDECL(10) WDECL(11) WDECL(12) WDECL(13) WDECL(14)
    WDECL(15) WDECL(16) WDECL(17) WDECL(18) WDECL(19)
    WDECL(20) WDECL(21) WDECL(22) WDECL(23) WDECL(24)
#undef WDECL
    const float wi0 = W_ih[row * 5 + 0];
    const float wi1 = W_ih[row * 5 + 1];
    const float wi2 = W_ih[row * 5 + 2];
    const float wi3 = W_ih[row * 5 + 3];
    const float wi4 = W_ih[row * 5 + 4];
    const float bias = b_ih[row] + b_hh[row];

    float c = 0.f;
    if (tid < 208) ((float*)hbuf)[tid] = 0.f;      // zero both h buffers
    __syncthreads();

    // x_t pipeline (uniform address -> scalar loads), 1-step lookahead
    float xc0 = input_seq[0];
    float xc1 = input_seq[1];
    float xc2 = input_seq[2];
    float xc3 = input_seq[3];
    float xc4 = input_seq[4];

    for (int t = 0; t < T_LEN; ++t) {
        const int tn = (t + 1 < T_LEN) ? (t + 1) : t;
        const float xn0 = input_seq[tn * 5 + 0];
        const float xn1 = input_seq[tn * 5 + 1];
        const float xn2 = input_seq[tn * 5 + 2];
        const float xn3 = input_seq[tn * 5 + 3];
        const float xn4 = input_seq[tn * 5 + 4];

        const float4* __restrict__ h4 = (const float4*)hbuf[t & 1];

        // z = bias + W_ih[row].x_t + W_hh[row].h   (4 independent FMA chains)
        float a0 = bias + wi0 * xc0 + wi1 * xc1 + wi2 * xc2 + wi3 * xc3 + wi4 * xc4;
        float a1 = 0.f, a2 = 0.f, a3 = 0.f;
#define MVQ(q) { const float4 hv = h4[q];                 \
                 a0 = fmaf(w##q.x, hv.x, a0);             \
                 a1 = fmaf(w##q.y, hv.y, a1);             \
                 a2 = fmaf(w##q.z, hv.z, a2);             \
                 a3 = fmaf(w##q.w, hv.w, a3); }
        MVQ(0)  MVQ(1)  MVQ(2)  MVQ(3)  MVQ(4)
        MVQ(5)  MVQ(6)  MVQ(7)  MVQ(8)  MVQ(9)
        MVQ(10) MVQ(11) MVQ(12) MVQ(13) MVQ(14)
        MVQ(15) MVQ(16) MVQ(17) MVQ(18) MVQ(19)
        MVQ(20) MVQ(21) MVQ(22) MVQ(23) MVQ(24)
#undef MVQ
        const float z = (a0 + a1) + (a2 + a3);

        // branchless nonlinearity: sigmoid(z) or tanh(z)=2*sigmoid(2z)-1
        const float u  = isg ? 2.f * z : z;
        const float e  = __expf(-u);
        const float sg = __builtin_amdgcn_rcpf(1.f + e);
        const float gv = isg ? (2.f * sg - 1.f) : sg;

        // gate exchange within the quad: VALU DPP quad_perm broadcasts
        const int gvi = __float_as_int(gv);
        const float iv = __int_as_float(__builtin_amdgcn_mov_dpp(gvi, 0x00, 0xf, 0xf, true)); // lane 0 of quad
        const float fv = __int_as_float(__builtin_amdgcn_mov_dpp(gvi, 0x55, 0xf, 0xf, true)); // lane 1
        const float gg = __int_as_float(__builtin_amdgcn_mov_dpp(gvi, 0xaa, 0xf, 0xf, true)); // lane 2
        const float ov = __int_as_float(__builtin_amdgcn_mov_dpp(gvi, 0xff, 0xf, 0xf, true)); // lane 3

        // replicated cell update (identical in all 4 lanes of the quad)
        c = fv * c + iv * gg;
        const float e2 = __expf(-2.f * c);
        const float th = 2.f * __builtin_amdgcn_rcpf(1.f + e2) - 1.f;
        const float hv = ov * th;

        if ((g == 0) & (j < HDIM)) hbuf[(t + 1) & 1][j] = hv;
        __syncthreads();   // single barrier per step

        xc0 = xn0; xc1 = xn1; xc2 = xn2; xc3 = xn3; xc4 = xn4;
    }

    // epilogue: out = b_lin + W_lin . h_T   (T_LEN even -> final h in hbuf[0])
    if (tid == 0) {
        float acc = b_lin[0];
        #pragma unroll
        for (int k = 0; k < HDIM; ++k) acc += W_lin[k] * hbuf[0][k];
        out[0] = acc;
    }
}

extern "C" void kernel_launch(void* const* d_in, const int* in_sizes, int n_in,
                              void* d_out, int out_size, void* d_ws, size_t ws_size,
                              hipStream_t stream) {
    const float* input_seq = (const float*)d_in[0];
    const float* W_ih      = (const float*)d_in[1];
    const float* W_hh      = (const float*)d_in[2];
    const float* b_ih      = (const float*)d_in[3];
    const float* b_hh      = (const float*)d_in[4];
    const float* W_lin     = (const float*)d_in[5];
    const float* b_lin     = (const float*)d_in[6];
    float* out = (float*)d_out;

    lstm_seq_kernel<<<1, 448, 0, stream>>>(input_seq, W_ih, W_hh, b_ih, b_hh,
                                           W_lin, b_lin, out);
}

// Round 3
// 95607.855 us; speedup vs baseline: 1.4429x; 1.2204x over previous
//
#include <hip/hip_runtime.h>

#define T_LEN 131072
#define HDIM  100

// Layout: 256 threads (4 waves), tid = 4*q + g. Quad q<50 owns hidden indices
// j0=q and j1=q+50; lane g owns gate g (0:i 1:f 2:g 3:o) for BOTH, i.e. rows
// 100g+q and 100g+q+50. Weights: 50 float4s in registers (loop-invariant).
// Per step: 25 broadcast ds_read_b128 of h (the per-CU LDS pipe cost:
// 4 waves x 25 x ~12cyc ~= 1200 cyc/step, the predicted new critical path),
// 8 fmacs per read, 2x gate nonlinearity, 8 DPP quad_perm exchanges,
// replicated c updates, lane g==0 writes both h values, ONE barrier
// (double-buffered h).

__global__ __launch_bounds__(256, 1)
void lstm_seq_kernel(const float* __restrict__ input_seq,
                     const float* __restrict__ W_ih,
                     const float* __restrict__ W_hh,
                     const float* __restrict__ b_ih,
                     const float* __restrict__ b_hh,
                     const float* __restrict__ W_lin,
                     const float* __restrict__ b_lin,
                     float* __restrict__ out)
{
    __shared__ __align__(16) float hbuf[2][104];   // double-buffered h

    const int tid = threadIdx.x;
    const int q   = tid >> 2;            // quad id 0..63
    const int g   = tid & 3;             // gate id
    const bool act = q < 50;
    const int qe  = act ? q : 0;         // clamp inactive quads to valid rows
    const int r0  = 100 * g + qe;        // row for hidden j0 = qe
    const int r1  = 100 * g + qe + 50;   // row for hidden j1 = qe+50
    const bool isg = (g == 2);           // tanh gate

    // ---- one-time: two weight rows into 50 named float4 registers ----
    const float4* __restrict__ wpA = (const float4*)(W_hh + r0 * HDIM);
    const float4* __restrict__ wpB = (const float4*)(W_hh + r1 * HDIM);
#define WDECL(k) const float4 wA##k = wpA[k]; const float4 wB##k = wpB[k];
    WDECL(0)  WDECL(1)  WDECL(2)  WDECL(3)  WDECL(4)
    WDECL(5)  WDECL(6)  WDECL(7)  WDECL(8)  WDECL(9)
    WDECL(10) WDECL(11) WDECL(12) WDECL(13) WDECL(14)
    WDECL(15) WDECL(16) WDECL(17) WDECL(18) WDECL(19)
    WDECL(20) WDECL(21) WDECL(22) WDECL(23) WDECL(24)
#undef WDECL
    const float wiA0 = W_ih[r0 * 5 + 0], wiB0 = W_ih[r1 * 5 + 0];
    const float wiA1 = W_ih[r0 * 5 + 1], wiB1 = W_ih[r1 * 5 + 1];
    const float wiA2 = W_ih[r0 * 5 + 2], wiB2 = W_ih[r1 * 5 + 2];
    const float wiA3 = W_ih[r0 * 5 + 3], wiB3 = W_ih[r1 * 5 + 3];
    const float wiA4 = W_ih[r0 * 5 + 4], wiB4 = W_ih[r1 * 5 + 4];
    const float biasA = b_ih[r0] + b_hh[r0];
    const float biasB = b_ih[r1] + b_hh[r1];

    float cA = 0.f, cB = 0.f;
    if (tid < 208) ((float*)hbuf)[tid] = 0.f;
    __syncthreads();

    // x_t pipeline (uniform address -> scalar loads), 1-step lookahead
    float xc0 = input_seq[0];
    float xc1 = input_seq[1];
    float xc2 = input_seq[2];
    float xc3 = input_seq[3];
    float xc4 = input_seq[4];

    for (int t = 0; t < T_LEN; ++t) {
        const int tn = (t + 1 < T_LEN) ? (t + 1) : t;
        const float xn0 = input_seq[tn * 5 + 0];
        const float xn1 = input_seq[tn * 5 + 1];
        const float xn2 = input_seq[tn * 5 + 2];
        const float xn3 = input_seq[tn * 5 + 3];
        const float xn4 = input_seq[tn * 5 + 4];

        const float4* __restrict__ h4 = (const float4*)hbuf[t & 1];

        // zA/zB = bias + W_ih[row].x + W_hh[row].h  (4 chains per row)
        float a0 = biasA + wiA0 * xc0 + wiA1 * xc1 + wiA2 * xc2 + wiA3 * xc3 + wiA4 * xc4;
        float b0 = biasB + wiB0 * xc0 + wiB1 * xc1 + wiB2 * xc2 + wiB3 * xc3 + wiB4 * xc4;
        float a1 = 0.f, a2 = 0.f, a3 = 0.f;
        float b1 = 0.f, b2 = 0.f, b3 = 0.f;
#define MVQ(k) { const float4 hv = h4[k];                  \
                 a0 = fmaf(wA##k.x, hv.x, a0);             \
                 a1 = fmaf(wA##k.y, hv.y, a1);             \
                 a2 = fmaf(wA##k.z, hv.z, a2);             \
                 a3 = fmaf(wA##k.w, hv.w, a3);             \
                 b0 = fmaf(wB##k.x, hv.x, b0);             \
                 b1 = fmaf(wB##k.y, hv.y, b1);             \
                 b2 = fmaf(wB##k.z, hv.z, b2);             \
                 b3 = fmaf(wB##k.w, hv.w, b3); }
        MVQ(0)  MVQ(1)  MVQ(2)  MVQ(3)  MVQ(4)
        MVQ(5)  MVQ(6)  MVQ(7)  MVQ(8)  MVQ(9)
        MVQ(10) MVQ(11) MVQ(12) MVQ(13) MVQ(14)
        MVQ(15) MVQ(16) MVQ(17) MVQ(18) MVQ(19)
        MVQ(20) MVQ(21) MVQ(22) MVQ(23) MVQ(24)
#undef MVQ
        const float zA = (a0 + a1) + (a2 + a3);
        const float zB = (b0 + b1) + (b2 + b3);

        // branchless nonlinearity: sigmoid(z), or tanh(z)=2*sigmoid(2z)-1
        const float uA  = isg ? 2.f * zA : zA;
        const float uB  = isg ? 2.f * zB : zB;
        const float eA  = __expf(-uA);
        const float eB  = __expf(-uB);
        const float sgA = __builtin_amdgcn_rcpf(1.f + eA);
        const float sgB = __builtin_amdgcn_rcpf(1.f + eB);
        const float gvA = isg ? (2.f * sgA - 1.f) : sgA;
        const float gvB = isg ? (2.f * sgB - 1.f) : sgB;

        // gate exchange within the quad (VALU DPP quad_perm broadcasts)
        const int giA = __float_as_int(gvA);
        const int giB = __float_as_int(gvB);
        const float ivA = __int_as_float(__builtin_amdgcn_mov_dpp(giA, 0x00, 0xf, 0xf, true));
        const float fvA = __int_as_float(__builtin_amdgcn_mov_dpp(giA, 0x55, 0xf, 0xf, true));
        const float ggA = __int_as_float(__builtin_amdgcn_mov_dpp(giA, 0xaa, 0xf, 0xf, true));
        const float ovA = __int_as_float(__builtin_amdgcn_mov_dpp(giA, 0xff, 0xf, 0xf, true));
        const float ivB = __int_as_float(__builtin_amdgcn_mov_dpp(giB, 0x00, 0xf, 0xf, true));
        const float fvB = __int_as_float(__builtin_amdgcn_mov_dpp(giB, 0x55, 0xf, 0xf, true));
        const float ggB = __int_as_float(__builtin_amdgcn_mov_dpp(giB, 0xaa, 0xf, 0xf, true));
        const float ovB = __int_as_float(__builtin_amdgcn_mov_dpp(giB, 0xff, 0xf, 0xf, true));

        // replicated cell updates (identical in all 4 lanes of the quad)
        cA = fvA * cA + ivA * ggA;
        cB = fvB * cB + ivB * ggB;
        const float e2A = __expf(-2.f * cA);
        const float e2B = __expf(-2.f * cB);
        const float thA = 2.f * __builtin_amdgcn_rcpf(1.f + e2A) - 1.f;
        const float thB = 2.f * __builtin_amdgcn_rcpf(1.f + e2B) - 1.f;
        const float hvA = ovA * thA;
        const float hvB = ovB * thB;

        float* __restrict__ hn = hbuf[(t + 1) & 1];
        if ((g == 0) & act) { hn[qe] = hvA; hn[qe + 50] = hvB; }
        __syncthreads();   // single barrier per step

        xc0 = xn0; xc1 = xn1; xc2 = xn2; xc3 = xn3; xc4 = xn4;
    }

    // epilogue: out = b_lin + W_lin . h_T   (T_LEN even -> final h in hbuf[0])
    if (tid == 0) {
        float acc = b_lin[0];
        #pragma unroll
        for (int k = 0; k < HDIM; ++k) acc += W_lin[k] * hbuf[0][k];
        out[0] = acc;
    }
}

extern "C" void kernel_launch(void* const* d_in, const int* in_sizes, int n_in,
                              void* d_out, int out_size, void* d_ws, size_t ws_size,
                              hipStream_t stream) {
    const float* input_seq = (const float*)d_in[0];
    const float* W_ih      = (const float*)d_in[1];
    const float* W_hh      = (const float*)d_in[2];
    const float* b_ih      = (const float*)d_in[3];
    const float* b_hh      = (const float*)d_in[4];
    const float* W_lin     = (const float*)d_in[5];
    const float* b_lin     = (const float*)d_in[6];
    float* out = (float*)d_out;

    lstm_seq_kernel<<<1, 256, 0, stream>>>(input_seq, W_ih, W_hh, b_ih, b_hh,
                                           W_lin, b_lin, out);
}

// Round 4
// 80016.840 us; speedup vs baseline: 1.7240x; 1.1948x over previous
//
#include <hip/hip_runtime.h>

#define T_LEN 131072
#define HDIM  100
#define LOG2E 1.4426950408889634f

// Layout: 256 threads (4 waves), tid = 4*q + g; quad q<50 owns hidden j0=q,
// j1=q+50; lane g owns gate g for both (rows 100g+q, 100g+q+50).
//
// R4 change: h-broadcast moved OFF the per-CU LDS pipe (R3's 1200cyc floor).
// Per wave: 2 lane-distributed ds_read_b32 bring h into 2 VGPRs, then 100
// v_readlane_b32 (per-SIMD parallel, 2cyc) lift h into SGPRs, and the matvec
// is v_fmac_f32 acc, s_h, v_w (SGPR operand free). Readlanes chunked 20-wide
// to cap SGPR pressure. Weights/bias pre-scaled by log2e (2*log2e for the
// tanh gate) so nonlinearities use raw exp2 with no argument multiply.

__device__ __forceinline__ float4 s4(float4 v, float s) {
    v.x *= s; v.y *= s; v.z *= s; v.w *= s; return v;
}

__global__ __launch_bounds__(256, 1)
void lstm_seq_kernel(const float* __restrict__ input_seq,
                     const float* __restrict__ W_ih,
                     const float* __restrict__ W_hh,
                     const float* __restrict__ b_ih,
                     const float* __restrict__ b_hh,
                     const float* __restrict__ W_lin,
                     const float* __restrict__ b_lin,
                     float* __restrict__ out)
{
    __shared__ __align__(16) float hbuf[2][128];   // double-buffered h (pad to 128)

    const int tid  = threadIdx.x;
    const int lane = tid & 63;
    const int q    = tid >> 2;           // quad id 0..63
    const int g    = tid & 3;            // gate id 0:i 1:f 2:g 3:o
    const bool act = q < 50;
    const int qe   = act ? q : 0;
    const int r0   = 100 * g + qe;
    const int r1   = r0 + 50;
    const bool isg = (g == 2);
    const float zscale = (isg ? 2.0f : 1.0f) * LOG2E;   // exp2-domain pre-scale

    // ---- one-time: two weight rows (pre-scaled) into named float4 regs ----
    const float4* __restrict__ wpA = (const float4*)(W_hh + r0 * HDIM);
    const float4* __restrict__ wpB = (const float4*)(W_hh + r1 * HDIM);
#define WDECL(k) const float4 wA##k = s4(wpA[k], zscale); const float4 wB##k = s4(wpB[k], zscale);
    WDECL(0)  WDECL(1)  WDECL(2)  WDECL(3)  WDECL(4)
    WDECL(5)  WDECL(6)  WDECL(7)  WDECL(8)  WDECL(9)
    WDECL(10) WDECL(11) WDECL(12) WDECL(13) WDECL(14)
    WDECL(15) WDECL(16) WDECL(17) WDECL(18) WDECL(19)
    WDECL(20) WDECL(21) WDECL(22) WDECL(23) WDECL(24)
#undef WDECL
    const float wiA0 = W_ih[r0 * 5 + 0] * zscale, wiB0 = W_ih[r1 * 5 + 0] * zscale;
    const float wiA1 = W_ih[r0 * 5 + 1] * zscale, wiB1 = W_ih[r1 * 5 + 1] * zscale;
    const float wiA2 = W_ih[r0 * 5 + 2] * zscale, wiB2 = W_ih[r1 * 5 + 2] * zscale;
    const float wiA3 = W_ih[r0 * 5 + 3] * zscale, wiB3 = W_ih[r1 * 5 + 3] * zscale;
    const float wiA4 = W_ih[r0 * 5 + 4] * zscale, wiB4 = W_ih[r1 * 5 + 4] * zscale;
    const float biasA = (b_ih[r0] + b_hh[r0]) * zscale;
    const float biasB = (b_ih[r1] + b_hh[r1]) * zscale;

    float cA = 0.f, cB = 0.f;
    ((float*)hbuf)[tid] = 0.f;           // zero both buffers (256 floats)
    __syncthreads();

    float xc0 = input_seq[0];
    float xc1 = input_seq[1];
    float xc2 = input_seq[2];
    float xc3 = input_seq[3];
    float xc4 = input_seq[4];

    for (int t = 0; t < T_LEN; ++t) {
        const int tn = (t + 1 < T_LEN) ? (t + 1) : t;
        const float xn0 = input_seq[tn * 5 + 0];
        const float xn1 = input_seq[tn * 5 + 1];
        const float xn2 = input_seq[tn * 5 + 2];
        const float xn3 = input_seq[tn * 5 + 3];
        const float xn4 = input_seq[tn * 5 + 4];

        // lane-distributed h read: 2 LDS instrs per wave (off the b128 path)
        const float* __restrict__ hb = hbuf[t & 1];
        const int h0i = __float_as_int(hb[lane]);
        const int h1i = __float_as_int(hb[64 + lane]);   // >99 garbage, never readlaned

        // x-projection (weights pre-scaled), overlaps the LDS latency
        float a0 = fmaf(wiA0, xc0, fmaf(wiA1, xc1, fmaf(wiA2, xc2, fmaf(wiA3, xc3, fmaf(wiA4, xc4, biasA)))));
        float b0 = fmaf(wiB0, xc0, fmaf(wiB1, xc1, fmaf(wiB2, xc2, fmaf(wiB3, xc3, fmaf(wiB4, xc4, biasB)))));
        float a1 = 0.f, a2 = 0.f, a3 = 0.f;
        float b1 = 0.f, b2 = 0.f, b3 = 0.f;

#define RL(j) __int_as_float((j) < 64 ? __builtin_amdgcn_readlane(h0i, (j)) \
                                      : __builtin_amdgcn_readlane(h1i, (j) - 64))
#define FM4(K, H0, H1, H2, H3)                          \
        a0 = fmaf(wA##K.x, H0, a0);                     \
        a1 = fmaf(wA##K.y, H1, a1);                     \
        a2 = fmaf(wA##K.z, H2, a2);                     \
        a3 = fmaf(wA##K.w, H3, a3);                     \
        b0 = fmaf(wB##K.x, H0, b0);                     \
        b1 = fmaf(wB##K.y, H1, b1);                     \
        b2 = fmaf(wB##K.z, H2, b2);                     \
        b3 = fmaf(wB##K.w, H3, b3);
#define CH(J, K0, K1, K2, K3, K4) {                                     \
        const float p0  = RL(J+0),  p1  = RL(J+1),  p2  = RL(J+2),  p3  = RL(J+3);  \
        const float p4  = RL(J+4),  p5  = RL(J+5),  p6  = RL(J+6),  p7  = RL(J+7);  \
        const float p8  = RL(J+8),  p9  = RL(J+9),  p10 = RL(J+10), p11 = RL(J+11); \
        const float p12 = RL(J+12), p13 = RL(J+13), p14 = RL(J+14), p15 = RL(J+15); \
        const float p16 = RL(J+16), p17 = RL(J+17), p18 = RL(J+18), p19 = RL(J+19); \
        FM4(K0, p0,  p1,  p2,  p3)                      \
        FM4(K1, p4,  p5,  p6,  p7)                      \
        FM4(K2, p8,  p9,  p10, p11)                     \
        FM4(K3, p12, p13, p14, p15)                     \
        FM4(K4, p16, p17, p18, p19) }

        CH(0,  0,  1,  2,  3,  4)
        CH(20, 5,  6,  7,  8,  9)
        CH(40, 10, 11, 12, 13, 14)
        CH(60, 15, 16, 17, 18, 19)
        CH(80, 20, 21, 22, 23, 24)
#undef CH
#undef FM4
#undef RL

        const float zA = (a0 + a1) + (a2 + a3);   // already in exp2 domain
        const float zB = (b0 + b1) + (b2 + b3);

        // sigmoid(z) = rcp(1+exp2(-z')); tanh path uses same form (row pre-scaled by 2log2e)
        const float eA  = __builtin_amdgcn_exp2f(-zA);
        const float eB  = __builtin_amdgcn_exp2f(-zB);
        const float sA  = __builtin_amdgcn_rcpf(1.f + eA);
        const float sB  = __builtin_amdgcn_rcpf(1.f + eB);
        const float gvA = isg ? fmaf(2.f, sA, -1.f) : sA;
        const float gvB = isg ? fmaf(2.f, sB, -1.f) : sB;

        // gate exchange within the quad (DPP quad_perm broadcasts)
        const int giA = __float_as_int(gvA);
        const int giB = __float_as_int(gvB);
        const float ivA = __int_as_float(__builtin_amdgcn_mov_dpp(giA, 0x00, 0xf, 0xf, true));
        const float fvA = __int_as_float(__builtin_amdgcn_mov_dpp(giA, 0x55, 0xf, 0xf, true));
        const float ggA = __int_as_float(__builtin_amdgcn_mov_dpp(giA, 0xaa, 0xf, 0xf, true));
        const float ovA = __int_as_float(__builtin_amdgcn_mov_dpp(giA, 0xff, 0xf, 0xf, true));
        const float ivB = __int_as_float(__builtin_amdgcn_mov_dpp(giB, 0x00, 0xf, 0xf, true));
        const float fvB = __int_as_float(__builtin_amdgcn_mov_dpp(giB, 0x55, 0xf, 0xf, true));
        const float ggB = __int_as_float(__builtin_amdgcn_mov_dpp(giB, 0xaa, 0xf, 0xf, true));
        const float ovB = __int_as_float(__builtin_amdgcn_mov_dpp(giB, 0xff, 0xf, 0xf, true));

        // replicated cell update; tanh(c) = 2*rcp(1+exp2(-2*log2e*c)) - 1
        cA = fmaf(fvA, cA, ivA * ggA);
        cB = fmaf(fvB, cB, ivB * ggB);
        const float thA = fmaf(2.f, __builtin_amdgcn_rcpf(1.f + __builtin_amdgcn_exp2f(cA * (-2.f * LOG2E))), -1.f);
        const float thB = fmaf(2.f, __builtin_amdgcn_rcpf(1.f + __builtin_amdgcn_exp2f(cB * (-2.f * LOG2E))), -1.f);
        const float hvA = ovA * thA;
        const float hvB = ovB * thB;

        float* __restrict__ hn = hbuf[(t + 1) & 1];
        if ((g == 0) & act) { hn[qe] = hvA; hn[qe + 50] = hvB; }
        __syncthreads();   // single barrier per step (double buffer -> race-free)

        xc0 = xn0; xc1 = xn1; xc2 = xn2; xc3 = xn3; xc4 = xn4;
    }

    // epilogue: out = b_lin + W_lin . h_T  (T_LEN even -> final h in hbuf[0])
    if (tid == 0) {
        float acc = b_lin[0];
        #pragma unroll
        for (int k = 0; k < HDIM; ++k) acc += W_lin[k] * hbuf[0][k];
        out[0] = acc;
    }
}

extern "C" void kernel_launch(void* const* d_in, const int* in_sizes, int n_in,
                              void* d_out, int out_size, void* d_ws, size_t ws_size,
                              hipStream_t stream) {
    const float* input_seq = (const float*)d_in[0];
    const float* W_ih      = (const float*)d_in[1];
    const float* W_hh      = (const float*)d_in[2];
    const float* b_ih      = (const float*)d_in[3];
    const float* b_hh      = (const float*)d_in[4];
    const float* W_lin     = (const float*)d_in[5];
    const float* b_lin     = (const float*)d_in[6];
    float* out = (float*)d_out;

    lstm_seq_kernel<<<1, 256, 0, stream>>>(input_seq, W_ih, W_hh, b_ih, b_hh,
                                           W_lin, b_lin, out);
}

// Round 6
// 64288.135 us; speedup vs baseline: 2.1458x; 1.2447x over previous
//
#include <hip/hip_runtime.h>

#define T_LEN 131072
#define HDIM  100
#define KPAD  112            // 100 h | 5 x | 1 bias-one | 6 zero
#define NTHR  512
#define LOG2E 1.4426950408889634f

typedef __attribute__((ext_vector_type(2))) float f32x2;

// Layout: 512 threads = 8 waves (2/SIMD). Quad j (lanes 4j..4j+3) owns hidden
// unit j (j<100 active). Lane g of the quad owns K-slice cols [28g, 28g+28) of
// the augmented K = [h(100) | x(5) | 1 | pad6]. Weights: 4 gate-rows x 28 cols
// = 112 floats/thread in registers (pre-scaled by log2e / 2log2e so the
// nonlinearity is raw exp2). Per step: 7 ds_read_b128 (h-slice), 56 v_pk_fma,
// 2-step quad DPP butterfly -> all 4 z's replicated in-quad, local cell update
// (c replicated x4, no gate exchange), lane0 writes h, lanes<5 write x_{t+1},
// ONE barrier (double-buffered LDS).

template <int PAT>
__device__ __forceinline__ float qdpp(float v) {
    return __int_as_float(__builtin_amdgcn_mov_dpp(__float_as_int(v), PAT, 0xf, 0xf, true));
}

__global__ __launch_bounds__(NTHR, 2)
void lstm_seq_kernel(const float* __restrict__ input_seq,
                     const float* __restrict__ W_ih,
                     const float* __restrict__ W_hh,
                     const float* __restrict__ b_ih,
                     const float* __restrict__ b_hh,
                     const float* __restrict__ W_lin,
                     const float* __restrict__ b_lin,
                     float* __restrict__ out)
{
    __shared__ __align__(16) float hbuf[2][KPAD];

    const int tid = threadIdx.x;
    const int j   = tid >> 2;            // quad id / hidden index 0..127
    const int g   = tid & 3;             // K-slice id
    const bool act = j < HDIM;
    const int je  = act ? j : 0;

    // ---- one-time: augmented, pre-scaled weight slice (4 rows x 28 cols) ----
    f32x2 w2[4][14];
    #pragma unroll
    for (int v = 0; v < 4; ++v) {
        const int row = v * HDIM + je;
        const float sc = (v == 2 ? 2.f : 1.f) * LOG2E;
        float tmp[28];
        #pragma unroll
        for (int cidx = 0; cidx < 28; ++cidx) {
            const int col = 28 * g + cidx;
            float wv;
            if      (col < HDIM)      wv = W_hh[row * HDIM + col];
            else if (col < HDIM + 5)  wv = W_ih[row * 5 + (col - HDIM)];
            else if (col == HDIM + 5) wv = b_ih[row] + b_hh[row];
            else                      wv = 0.f;
            tmp[cidx] = wv * sc;
        }
        #pragma unroll
        for (int k = 0; k < 14; ++k) { w2[v][k].x = tmp[2 * k]; w2[v][k].y = tmp[2 * k + 1]; }
    }

    // ---- init LDS: h=0 both buffers, x_0 in buf0, bias-one in both ----
    if (tid < 2 * KPAD) ((float*)hbuf)[tid] = 0.f;
    __syncthreads();
    if (tid < 5) hbuf[0][HDIM + tid] = input_seq[tid];
    if (tid == 5) { hbuf[0][HDIM + 5] = 1.f; hbuf[1][HDIM + 5] = 1.f; }
    __syncthreads();

    float c = 0.f;                       // cell state, replicated in the quad

    for (int t = 0; t < T_LEN; ++t) {
        // prefetch next x (5 lanes), latency hidden under the matvec
        float xn = 0.f;
        if (tid < 5) {
            const int tn = (t + 1 < T_LEN) ? (t + 1) : (T_LEN - 1);
            xn = input_seq[tn * 5 + tid];
        }

        // h-slice: 7 x ds_read_b128 -> 14 f32x2
        const float4* __restrict__ hp = (const float4*)(hbuf[t & 1] + 28 * g);
        const float4 q0 = hp[0], q1 = hp[1], q2 = hp[2], q3 = hp[3];
        const float4 q4 = hp[4], q5 = hp[5], q6 = hp[6];
        f32x2 hh[14];
        hh[0]  = f32x2{q0.x, q0.y}; hh[1]  = f32x2{q0.z, q0.w};
        hh[2]  = f32x2{q1.x, q1.y}; hh[3]  = f32x2{q1.z, q1.w};
        hh[4]  = f32x2{q2.x, q2.y}; hh[5]  = f32x2{q2.z, q2.w};
        hh[6]  = f32x2{q3.x, q3.y}; hh[7]  = f32x2{q3.z, q3.w};
        hh[8]  = f32x2{q4.x, q4.y}; hh[9]  = f32x2{q4.z, q4.w};
        hh[10] = f32x2{q5.x, q5.y}; hh[11] = f32x2{q5.z, q5.w};
        hh[12] = f32x2{q6.x, q6.y}; hh[13] = f32x2{q6.z, q6.w};

        // 4 gate-row partials over the 28-col slice (packed fp32 fma)
        f32x2 p20 = f32x2{0.f, 0.f}, p21 = f32x2{0.f, 0.f};
        f32x2 p22 = f32x2{0.f, 0.f}, p23 = f32x2{0.f, 0.f};
        #pragma unroll
        for (int k = 0; k < 14; ++k) {
            p20 = hh[k] * w2[0][k] + p20;
            p21 = hh[k] * w2[1][k] + p21;
            p22 = hh[k] * w2[2][k] + p22;
            p23 = hh[k] * w2[3][k] + p23;
        }
        float p0 = p20.x + p20.y;
        float p1 = p21.x + p21.y;
        float p2 = p22.x + p22.y;
        float p3 = p23.x + p23.y;

        // quad butterfly: after xor1+xor2 every lane holds full z0..z3
        p0 += qdpp<0xB1>(p0); p1 += qdpp<0xB1>(p1);   // quad_perm(1,0,3,2)
        p2 += qdpp<0xB1>(p2); p3 += qdpp<0xB1>(p3);
        p0 += qdpp<0x4E>(p0); p1 += qdpp<0x4E>(p1);   // quad_perm(2,3,0,1)
        p2 += qdpp<0x4E>(p2); p3 += qdpp<0x4E>(p3);

        // gates (rows pre-scaled: sigmoid rows by log2e, tanh row by 2log2e)
        const float si = __builtin_amdgcn_rcpf(1.f + __builtin_amdgcn_exp2f(-p0));
        const float sf = __builtin_amdgcn_rcpf(1.f + __builtin_amdgcn_exp2f(-p1));
        const float gg = fmaf(2.f, __builtin_amdgcn_rcpf(1.f + __builtin_amdgcn_exp2f(-p2)), -1.f);
        const float so = __builtin_amdgcn_rcpf(1.f + __builtin_amdgcn_exp2f(-p3));

        // cell update (replicated across the quad's 4 lanes)
        c = fmaf(sf, c, si * gg);
        const float th = fmaf(2.f, __builtin_amdgcn_rcpf(1.f + __builtin_amdgcn_exp2f(c * (-2.f * LOG2E))), -1.f);
        const float hv = so * th;

        float* __restrict__ hn = hbuf[(t + 1) & 1];
        if ((g == 0) & act) hn[j] = hv;
        if (tid < 5) hn[HDIM + tid] = xn;
        __syncthreads();                 // single barrier per step
    }

    // epilogue: out = b_lin + W_lin . h_T   (T_LEN even -> h_T in hbuf[0])
    if (tid == 0) {
        float acc = b_lin[0];
        #pragma unroll
        for (int k = 0; k < HDIM; ++k) acc += W_lin[k] * hbuf[0][k];
        out[0] = acc;
    }
}

extern "C" void kernel_launch(void* const* d_in, const int* in_sizes, int n_in,
                              void* d_out, int out_size, void* d_ws, size_t ws_size,
                              hipStream_t stream) {
    const float* input_seq = (const float*)d_in[0];
    const float* W_ih      = (const float*)d_in[1];
    const float* W_hh      = (const float*)d_in[2];
    const float* b_ih      = (const float*)d_in[3];
    const float* b_hh      = (const float*)d_in[4];
    const float* W_lin     = (const float*)d_in[5];
    const float* b_lin     = (const float*)d_in[6];
    float* out = (float*)d_out;

    lstm_seq_kernel<<<1, NTHR, 0, stream>>>(input_seq, W_ih, W_hh, b_ih, b_hh,
                                            W_lin, b_lin, out);
}